// Round 2
// baseline (206.678 us; speedup 1.0000x reference)
//
#include <hip/hip_runtime.h>
#include <math.h>

// loss = mean_b[ 0.5*nrmse(o1,t1) + 0.25*nrmse(o2,t2) + 0.25*nrmse(o3,t3) ]
// B=4096 rows, N=2048 fp32. Memory-bound: 201.3 MB in, 4 B out.
// Roofline: ~32 us at 6.3 TB/s HBM; less if L3 keeps supplying ~half the reads.
//
// R1 finding: VGPR_Count=32 -> compiler serialized the loads (~0.5 outstanding
// loads/wave by Little's law), kernel latency-bound at 2.7 TB/s effective.
// R2 change: batch-load the whole row into registers (16x float4 in flight)
// before computing. Deliberately spend VGPRs to buy MLP.
constexpr int N_ELEM = 2048;
constexpr int BATCH  = 4096;
constexpr int BLOCK  = 256;                   // 4 waves/block
constexpr int TASKS  = 3 * BATCH;             // 12288 (pair,row) tasks
constexpr int GRID1  = TASKS / (BLOCK / 64);  // 3072 blocks, 1 task/wave

__global__ __launch_bounds__(BLOCK)
void wnrmse_stage1(const float* __restrict__ o1, const float* __restrict__ t1,
                   const float* __restrict__ o2, const float* __restrict__ t2,
                   const float* __restrict__ o3, const float* __restrict__ t3,
                   float* __restrict__ partial)
{
    const int tid  = threadIdx.x;
    const int wave = tid >> 6;
    const int lane = tid & 63;
    const int task = blockIdx.x * (BLOCK / 64) + wave;   // global wave id == task

    const int pair = task >> 12;          // wave-uniform
    const int row  = task & (BATCH - 1);

    // Wave-uniform branchless pointer select -> scalar cselect, no scratch.
    const float* ob = (pair == 0) ? o1 : ((pair == 1) ? o2 : o3);
    const float* tb = (pair == 0) ? t1 : ((pair == 1) ? t2 : t3);
    const float  wgt = (pair == 0) ? 0.50f : 0.25f;

    const float4* o4 = (const float4*)(ob + (size_t)row * N_ELEM) + lane;
    const float4* t4 = (const float4*)(tb + (size_t)row * N_ELEM) + lane;

    // ---- Phase 1: issue ALL 16 loads before any use. Full static unroll so
    // every array index is compile-time (registers, not scratch — rule #20).
    float4 ov[8], tv[8];
#pragma unroll
    for (int j = 0; j < 8; ++j) ov[j] = o4[j * 64];
#pragma unroll
    for (int j = 0; j < 8; ++j) tv[j] = t4[j * 64];

    // ---- Phase 2: compute. Split accumulators to shorten dep chains.
    float ssd0 = 0.0f, ssd1 = 0.0f;
    float tmax0 = -INFINITY, tmax1 = -INFINITY;
    float tmin0 =  INFINITY, tmin1 =  INFINITY;
#pragma unroll
    for (int j = 0; j < 8; ++j) {
        float d0 = ov[j].x - tv[j].x;
        float d1 = ov[j].y - tv[j].y;
        float d2 = ov[j].z - tv[j].z;
        float d3 = ov[j].w - tv[j].w;
        ssd0 += d0 * d0 + d1 * d1;
        ssd1 += d2 * d2 + d3 * d3;
        tmax0 = fmaxf(tmax0, fmaxf(tv[j].x, tv[j].y));
        tmax1 = fmaxf(tmax1, fmaxf(tv[j].z, tv[j].w));
        tmin0 = fminf(tmin0, fminf(tv[j].x, tv[j].y));
        tmin1 = fminf(tmin1, fminf(tv[j].z, tv[j].w));
    }
    float ssd  = ssd0 + ssd1;
    float tmax = fmaxf(tmax0, tmax1);
    float tmin = fminf(tmin0, tmin1);

    // Wave-64 butterfly reduce; all lanes end with the row result.
#pragma unroll
    for (int off = 32; off > 0; off >>= 1) {
        ssd  += __shfl_xor(ssd, off, 64);
        tmax  = fmaxf(tmax, __shfl_xor(tmax, off, 64));
        tmin  = fminf(tmin, __shfl_xor(tmin, off, 64));
    }

    const float rmse  = sqrtf(ssd * (1.0f / (float)N_ELEM));
    const float local = wgt * rmse / (tmax - tmin);

    // Per-block combine, one plain store per block.
    __shared__ float s_part[BLOCK / 64];
    if (lane == 0) s_part[wave] = local;
    __syncthreads();
    if (tid == 0) {
        partial[blockIdx.x] = s_part[0] + s_part[1] + s_part[2] + s_part[3];
    }
}

// Stage 2: one block reduces GRID1 partials and writes the final scalar.
__global__ __launch_bounds__(BLOCK)
void wnrmse_stage2(const float* __restrict__ partial, float* __restrict__ out)
{
    const int tid = threadIdx.x;
    float s = 0.0f;
    for (int i = tid; i < GRID1; i += BLOCK) s += partial[i];

#pragma unroll
    for (int off = 32; off > 0; off >>= 1) s += __shfl_xor(s, off, 64);

    __shared__ float s_part[BLOCK / 64];
    const int wave = tid >> 6;
    const int lane = tid & 63;
    if (lane == 0) s_part[wave] = s;
    __syncthreads();
    if (tid == 0) {
        float tot = s_part[0] + s_part[1] + s_part[2] + s_part[3];
        out[0] = tot * (1.0f / (float)BATCH);
    }
}

extern "C" void kernel_launch(void* const* d_in, const int* in_sizes, int n_in,
                              void* d_out, int out_size, void* d_ws, size_t ws_size,
                              hipStream_t stream) {
    const float* o1 = (const float*)d_in[0];
    const float* t1 = (const float*)d_in[1];
    const float* o2 = (const float*)d_in[2];
    const float* t2 = (const float*)d_in[3];
    const float* o3 = (const float*)d_in[4];
    const float* t3 = (const float*)d_in[5];
    float* out     = (float*)d_out;
    float* partial = (float*)d_ws;    // GRID1 floats = 12 KiB, fully overwritten

    wnrmse_stage1<<<GRID1, BLOCK, 0, stream>>>(o1, t1, o2, t2, o3, t3, partial);
    wnrmse_stage2<<<1, BLOCK, 0, stream>>>(partial, out);
}

// Round 5
// 203.325 us; speedup vs baseline: 1.0165x; 1.0165x over previous
//
#include <hip/hip_runtime.h>
#include <math.h>

// loss = mean_b[ 0.5*nrmse(o1,t1) + 0.25*nrmse(o2,t2) + 0.25*nrmse(o3,t3) ]
// B=4096 rows, N=2048 fp32. 201.3 MB in, 4 B out. Roofline ~32 us @6.3 TB/s.
//
// R1: VGPR=32, loads serialized -> 74 us (2.7 TB/s effective read).
// R2: source-level batch-load reverted by scheduler (VGPR still 32, same t).
// R3: asm batch-load CRASHED: outputs lacked early-clobber, so load returns
//     could overwrite the t_lo/t_hi address pair before later loads issued.
// R4: early-clobber fix; container failed on infra (same signature as R0's
//     infra failure, no core dump) -> experiment never ran. Resubmitting
//     UNCHANGED so the VGPR/duration reading stays a clean A/B vs R1.
constexpr int N_ELEM = 2048;
constexpr int BATCH  = 4096;
constexpr int BLOCK  = 256;                   // 4 waves/block
constexpr int TASKS  = 3 * BATCH;             // 12288 (pair,row) tasks
constexpr int GRID1  = TASKS / (BLOCK / 64);  // 3072 blocks, 1 task/wave

typedef float f32x4 __attribute__((ext_vector_type(4)));

__global__ __launch_bounds__(BLOCK)
void wnrmse_stage1(const float* __restrict__ o1, const float* __restrict__ t1,
                   const float* __restrict__ o2, const float* __restrict__ t2,
                   const float* __restrict__ o3, const float* __restrict__ t3,
                   float* __restrict__ partial)
{
    const int tid  = threadIdx.x;
    const int wave = tid >> 6;
    const int lane = tid & 63;
    const int task = blockIdx.x * (BLOCK / 64) + wave;   // global wave id == task

    const int pair = task >> 12;          // wave-uniform
    const int row  = task & (BATCH - 1);

    const float* ob = (pair == 0) ? o1 : ((pair == 1) ? o2 : o3);
    const float* tb = (pair == 0) ? t1 : ((pair == 1) ? t2 : t3);
    const float  wgt = (pair == 0) ? 0.50f : 0.25f;

    // Chunk j (j=0..7) for this lane: byte offset lane*16 + j*1024 from row
    // base. 13-bit signed imm covers j=0..3 per base -> lo and hi(+4096B).
    const float* o_lo = ob + (size_t)row * N_ELEM + lane * 4;
    const float* o_hi = o_lo + 1024;   // +4096 bytes
    const float* t_lo = tb + (size_t)row * N_ELEM + lane * 4;
    const float* t_hi = t_lo + 1024;

    f32x4 ov0, ov1, ov2, ov3, ov4, ov5, ov6, ov7;
    f32x4 tv0, tv1, tv2, tv3, tv4, tv5, tv6, tv7;

    // All 16 loads issued back-to-back; ONE waitcnt at the end of the block.
    // 16 KB outstanding per wave. "=&v" (early-clobber) is REQUIRED: load
    // returns arrive while later loads still read the address inputs.
    asm volatile(
        "global_load_dwordx4 %0,  %[olo], off\n\t"
        "global_load_dwordx4 %1,  %[olo], off offset:1024\n\t"
        "global_load_dwordx4 %2,  %[olo], off offset:2048\n\t"
        "global_load_dwordx4 %3,  %[olo], off offset:3072\n\t"
        "global_load_dwordx4 %4,  %[ohi], off\n\t"
        "global_load_dwordx4 %5,  %[ohi], off offset:1024\n\t"
        "global_load_dwordx4 %6,  %[ohi], off offset:2048\n\t"
        "global_load_dwordx4 %7,  %[ohi], off offset:3072\n\t"
        "global_load_dwordx4 %8,  %[tlo], off\n\t"
        "global_load_dwordx4 %9,  %[tlo], off offset:1024\n\t"
        "global_load_dwordx4 %10, %[tlo], off offset:2048\n\t"
        "global_load_dwordx4 %11, %[tlo], off offset:3072\n\t"
        "global_load_dwordx4 %12, %[thi], off\n\t"
        "global_load_dwordx4 %13, %[thi], off offset:1024\n\t"
        "global_load_dwordx4 %14, %[thi], off offset:2048\n\t"
        "global_load_dwordx4 %15, %[thi], off offset:3072\n\t"
        "s_waitcnt vmcnt(0)"
        : "=&v"(ov0), "=&v"(ov1), "=&v"(ov2), "=&v"(ov3),
          "=&v"(ov4), "=&v"(ov5), "=&v"(ov6), "=&v"(ov7),
          "=&v"(tv0), "=&v"(tv1), "=&v"(tv2), "=&v"(tv3),
          "=&v"(tv4), "=&v"(tv5), "=&v"(tv6), "=&v"(tv7)
        : [olo] "v"(o_lo), [ohi] "v"(o_hi),
          [tlo] "v"(t_lo), [thi] "v"(t_hi)
        : "memory");

    // Compute phase. Split accumulators to shorten dep chains.
    float ssd0 = 0.0f, ssd1 = 0.0f;
    float tmax0 = -INFINITY, tmax1 = -INFINITY;
    float tmin0 =  INFINITY, tmin1 =  INFINITY;

#define ACC(OV, TV)                                                       \
    {                                                                     \
        float d0 = OV[0] - TV[0];                                         \
        float d1 = OV[1] - TV[1];                                         \
        float d2 = OV[2] - TV[2];                                         \
        float d3 = OV[3] - TV[3];                                         \
        ssd0 += d0 * d0 + d1 * d1;                                        \
        ssd1 += d2 * d2 + d3 * d3;                                        \
        tmax0 = fmaxf(tmax0, fmaxf(TV[0], TV[1]));                        \
        tmax1 = fmaxf(tmax1, fmaxf(TV[2], TV[3]));                        \
        tmin0 = fminf(tmin0, fminf(TV[0], TV[1]));                        \
        tmin1 = fminf(tmin1, fminf(TV[2], TV[3]));                        \
    }
    ACC(ov0, tv0) ACC(ov1, tv1) ACC(ov2, tv2) ACC(ov3, tv3)
    ACC(ov4, tv4) ACC(ov5, tv5) ACC(ov6, tv6) ACC(ov7, tv7)
#undef ACC

    float ssd  = ssd0 + ssd1;
    float tmax = fmaxf(tmax0, tmax1);
    float tmin = fminf(tmin0, tmin1);

    // Wave-64 butterfly reduce; all lanes end with the row result.
#pragma unroll
    for (int off = 32; off > 0; off >>= 1) {
        ssd  += __shfl_xor(ssd, off, 64);
        tmax  = fmaxf(tmax, __shfl_xor(tmax, off, 64));
        tmin  = fminf(tmin, __shfl_xor(tmin, off, 64));
    }

    const float rmse  = sqrtf(ssd * (1.0f / (float)N_ELEM));
    const float local = wgt * rmse / (tmax - tmin);

    // Per-block combine, one plain store per block.
    __shared__ float s_part[BLOCK / 64];
    if (lane == 0) s_part[wave] = local;
    __syncthreads();
    if (tid == 0) {
        partial[blockIdx.x] = s_part[0] + s_part[1] + s_part[2] + s_part[3];
    }
}

// Stage 2: one block reduces GRID1 partials and writes the final scalar.
__global__ __launch_bounds__(BLOCK)
void wnrmse_stage2(const float* __restrict__ partial, float* __restrict__ out)
{
    const int tid = threadIdx.x;
    float s = 0.0f;
    for (int i = tid; i < GRID1; i += BLOCK) s += partial[i];

#pragma unroll
    for (int off = 32; off > 0; off >>= 1) s += __shfl_xor(s, off, 64);

    __shared__ float s_part[BLOCK / 64];
    const int wave = tid >> 6;
    const int lane = tid & 63;
    if (lane == 0) s_part[wave] = s;
    __syncthreads();
    if (tid == 0) {
        float tot = s_part[0] + s_part[1] + s_part[2] + s_part[3];
        out[0] = tot * (1.0f / (float)BATCH);
    }
}

extern "C" void kernel_launch(void* const* d_in, const int* in_sizes, int n_in,
                              void* d_out, int out_size, void* d_ws, size_t ws_size,
                              hipStream_t stream) {
    const float* o1 = (const float*)d_in[0];
    const float* t1 = (const float*)d_in[1];
    const float* o2 = (const float*)d_in[2];
    const float* t2 = (const float*)d_in[3];
    const float* o3 = (const float*)d_in[4];
    const float* t3 = (const float*)d_in[5];
    float* out     = (float*)d_out;
    float* partial = (float*)d_ws;    // GRID1 floats = 12 KiB, fully overwritten

    wnrmse_stage1<<<GRID1, BLOCK, 0, stream>>>(o1, t1, o2, t2, o3, t3, partial);
    wnrmse_stage2<<<1, BLOCK, 0, stream>>>(partial, out);
}